// Round 2
// baseline (657.938 us; speedup 1.0000x reference)
//
#include <hip/hip_runtime.h>

// FFT long conv: out[b,d,l] = (1/16384) * sum_m x[b,d,m] f[b,d,l-m], masked by positions!=-1.
// One workgroup per (b,d) channel. Complex FFT size 8192 in 64KB LDS, radix-2 in-place.
// Forward DIF (natural -> bit-reversed), pointwise done in bit-reversed domain,
// inverse DIT (bit-reversed -> natural). No permute passes needed.
//
// NOTE: positions is int64 in the reference, but the harness delivers integer
// inputs as int32 ("integer -> const int*"). Reading it as long long was R1's
// bug (mask never fired -> absmax 1.8e-2).

#define N_FFT 8192
#define LOG2N 13
#define NT    1024          // threads per block
#define NPT   8             // elements per thread  (N_FFT / NT)
#define NBFLY 4             // butterflies per thread per stage (N_FFT/2 / NT)
#define PI_F  3.14159265358979323846f

__device__ __forceinline__ float2 cmul(float2 a, float2 b) {
    return make_float2(a.x * b.x - a.y * b.y, a.x * b.y + a.y * b.x);
}

__device__ __forceinline__ int rev13(int v) {
    return (int)(__brev((unsigned)v) >> 19);
}

// radix-2 DIF, natural input -> bit-reversed output, twiddle e^{-i*pi*j/half}
__device__ __forceinline__ void fft_fwd(float2* a, int t) {
    for (int s = LOG2N - 1; s >= 0; --s) {
        const int half = 1 << s;
        const float ang = -PI_F / (float)half;
#pragma unroll
        for (int q = 0; q < NBFLY; ++q) {
            const int bt = q * NT + t;            // butterfly id in [0, N/2)
            const int j  = bt & (half - 1);
            const int i  = ((bt >> s) << (s + 1)) | j;
            float2 u = a[i];
            float2 v = a[i + half];
            a[i] = make_float2(u.x + v.x, u.y + v.y);
            float sn, cs;
            __sincosf(ang * (float)j, &sn, &cs);
            float2 d = make_float2(u.x - v.x, u.y - v.y);
            a[i + half] = cmul(d, make_float2(cs, sn));
        }
        __syncthreads();
    }
}

// radix-2 DIT, bit-reversed input -> natural output, twiddle e^{+i*pi*j/half}, unscaled
__device__ __forceinline__ void fft_inv(float2* a, int t) {
    for (int s = 0; s < LOG2N; ++s) {
        const int half = 1 << s;
        const float ang = PI_F / (float)half;
#pragma unroll
        for (int q = 0; q < NBFLY; ++q) {
            const int bt = q * NT + t;
            const int j  = bt & (half - 1);
            const int i  = ((bt >> s) << (s + 1)) | j;
            float sn, cs;
            __sincosf(ang * (float)j, &sn, &cs);
            float2 u = a[i];
            float2 v = cmul(a[i + half], make_float2(cs, sn));
            a[i]        = make_float2(u.x + v.x, u.y + v.y);
            a[i + half] = make_float2(u.x - v.x, u.y - v.y);
        }
        __syncthreads();
    }
}

// Given Z1 = W_k, Z2 = W_{N-k} (both from the combined x+i*f spectrum),
// return Yhat_k = Xhat_k * Fhat_k * scale. (Yhat_{N-k} = conj(Yhat_k).)
__device__ __forceinline__ float2 pointwise(float2 z1, float2 z2, float scale) {
    float2 X = make_float2(0.5f * (z1.x + z2.x), 0.5f * (z1.y - z2.y));   // (Z1+conj(Z2))/2
    float2 D = make_float2(z1.x - z2.x, z1.y + z2.y);                     //  Z1-conj(Z2)
    float2 F = make_float2(0.5f * D.y, -0.5f * D.x);                      //  D/(2i)
    float2 Y = cmul(X, F);
    return make_float2(Y.x * scale, Y.y * scale);
}

__global__ void __launch_bounds__(NT)
fftconv_kernel(const float* __restrict__ x, const float* __restrict__ f,
               const int* __restrict__ pos, float* __restrict__ out) {
    __shared__ float2 a[N_FFT];                      // 64 KiB
    const int t = threadIdx.x;
    const int c = blockIdx.x;                        // channel b*256 + d
    const int b = c >> 8;
    const size_t base = (size_t)c * N_FFT;
    const int* pbase = pos + (size_t)b * N_FFT;

    const float scale = 1.0f / (16384.0f * 16384.0f);  // two forward-norm 1/n factors

    float2 w[NPT];      // stashed packed input (x + i f)
    float  yr[NPT];     // stashed Re(ye)

    // ---- load x,f; pack w = x + i f (natural order) ----
#pragma unroll
    for (int r = 0; r < NPT; ++r) {
        const int m = r * NT + t;
        w[r] = make_float2(x[base + m], f[base + m]);
        a[m] = w[r];
    }
    __syncthreads();

    // ---- even spectrum: E = FFT_8192(w_lo), in bit-reversed order ----
    fft_fwd(a, t);

    // ---- even pointwise: global k = 2j, partner N-k = 2*(8192-j) ----
#pragma unroll
    for (int q = 0; q < NBFLY; ++q) {
        const int j = q * NT + t;                    // 0..4095
        if (j == 0) {
            // self-pairs k'=0 and k'=4096
            {
                const int p = 0;                     // rev13(0)
                float2 z = a[p];
                a[p] = pointwise(z, z, scale);
            }
            {
                const int p = 1;                     // rev13(4096)
                float2 z = a[p];
                a[p] = pointwise(z, z, scale);
            }
        } else {
            const int p1 = rev13(j);
            const int p2 = rev13(N_FFT - j);
            float2 z1 = a[p1];
            float2 z2 = a[p2];
            float2 Y  = pointwise(z1, z2, scale);
            a[p1] = Y;
            a[p2] = make_float2(Y.x, -Y.y);          // hermitian partner
        }
    }
    __syncthreads();

    // ---- ye = IDFT_8192(Yhat_even), natural order; keep Re ----
    fft_inv(a, t);
#pragma unroll
    for (int r = 0; r < NPT; ++r) yr[r] = a[r * NT + t].x;
    __syncthreads();

    // ---- odd spectrum: O = FFT_8192(w_lo * e^{-2pi i m / 16384}) ----
    const float wang = -2.0f * PI_F / 16384.0f;
#pragma unroll
    for (int r = 0; r < NPT; ++r) {
        const int m = r * NT + t;
        float sn, cs;
        __sincosf(wang * (float)m, &sn, &cs);
        a[m] = cmul(w[r], make_float2(cs, sn));
    }
    __syncthreads();
    fft_fwd(a, t);

    // ---- odd pointwise: global k = 2j+1, partner N-k -> odd index 8191-j ----
#pragma unroll
    for (int q = 0; q < NBFLY; ++q) {
        const int j  = q * NT + t;                   // 0..4095, all proper pairs
        const int p1 = rev13(j);
        const int p2 = rev13(N_FFT - 1 - j);
        float2 z1 = a[p1];
        float2 z2 = a[p2];
        float2 Y  = pointwise(z1, z2, scale);
        a[p1] = Y;
        a[p2] = make_float2(Y.x, -Y.y);
    }
    __syncthreads();

    // ---- yo = IDFT_8192(Yhat_odd), natural order ----
    fft_inv(a, t);

    // ---- combine y_m = Re(ye_m) + Re(e^{+2pi i m/16384} yo_m), mask, store ----
    const float oang = 2.0f * PI_F / 16384.0f;
#pragma unroll
    for (int r = 0; r < NPT; ++r) {
        const int m = r * NT + t;
        float sn, cs;
        __sincosf(oang * (float)m, &sn, &cs);
        float2 yo = a[m];
        float val = yr[r] + cs * yo.x - sn * yo.y;
        float mask = (pbase[m] != -1) ? 1.0f : 0.0f;
        out[base + m] = val * mask;
    }
}

extern "C" void kernel_launch(void* const* d_in, const int* in_sizes, int n_in,
                              void* d_out, int out_size, void* d_ws, size_t ws_size,
                              hipStream_t stream) {
    const float* x   = (const float*)d_in[0];
    const float* f   = (const float*)d_in[1];
    const int*   pos = (const int*)d_in[2];
    float*       out = (float*)d_out;
    (void)in_sizes; (void)n_in; (void)out_size; (void)d_ws; (void)ws_size;

    // B*D = 8*256 = 2048 channels, one block each
    fftconv_kernel<<<2048, NT, 0, stream>>>(x, f, pos, out);
}